// Round 4
// baseline (236.560 us; speedup 1.0000x reference)
//
#include <hip/hip_runtime.h>

#define NB 256
#define NT 1024
#define NL 64

typedef __fp16 h2v __attribute__((ext_vector_type(2)));

__device__ __forceinline__ float rfl_f(float v) {
  return __builtin_bit_cast(float, __builtin_amdgcn_readfirstlane(__builtin_bit_cast(int, v)));
}

// DPP self-permute: result[l] = v[l ^ m] within a 16-lane row (xor-type ctrls).
// HW-verified (rounds 2/3, absmax=0).
#define DPPI(V, C) __builtin_amdgcn_update_dpp(V, V, C, 0xF, 0xF, false)

// Named-scalar butterfly: P##1..P##15 from root P##0 over masks {15,7,3,1}.
// Named scalars, never arrays (rule #20: arrays -> scratch, rounds 1/2).
#define TREE15(P)                                                             \
  int P##1 = DPPI(P##0, 0x140);                                               \
  int P##2 = DPPI(P##0, 0x141);                                               \
  int P##3 = DPPI(P##1, 0x141);                                               \
  int P##4 = DPPI(P##0, 0x1B);                                                \
  int P##5 = DPPI(P##1, 0x1B);                                                \
  int P##6 = DPPI(P##2, 0x1B);                                                \
  int P##7 = DPPI(P##3, 0x1B);                                                \
  int P##8 = DPPI(P##0, 0xB1);                                                \
  int P##9 = DPPI(P##1, 0xB1);                                                \
  int P##10 = DPPI(P##2, 0xB1);                                               \
  int P##11 = DPPI(P##3, 0xB1);                                               \
  int P##12 = DPPI(P##4, 0xB1);                                               \
  int P##13 = DPPI(P##5, 0xB1);                                               \
  int P##14 = DPPI(P##6, 0xB1);                                               \
  int P##15 = DPPI(P##7, 0xB1);

#define FD(S, T, RH) S = __builtin_amdgcn_fdot2(__builtin_bit_cast(h2v, T), RH, S, false)

// One CRF step. P is a LITERAL 0/1 (dead branch eliminated; loops are manually
// unswitched below). P=1: pure-VALU gather via permlane32/16_swap (cross-row
// exchange on the VALU pipe, ~8cy, vs ~230cy DS round trip). P=0: verified
// bpermute fallback. Slot->state correspondence is NOT assumed: Rh was loaded
// in the order reported by the index probe (below), so any deterministic
// permlane semantics is auto-compensated.
// Renorm: K = 2^(115-e8) from lane0's f32 exponent (verified r2/r3).
#define CRF_STEP(EF, P)                                                       \
  do {                                                                        \
    int wi = __builtin_bit_cast(int, w);                                      \
    int e8 = (__builtin_amdgcn_readfirstlane(wi) >> 23) & 0xff;               \
    float K = __builtin_bit_cast(float, (242 - e8) << 23);                    \
    float KE = K * (EF);                                                      \
    e2 += e8 - 115;                                                           \
    int tA0, tB0;                                                             \
    if (P) {                                                                  \
      auto uu = __builtin_amdgcn_permlane32_swap(wi, wi, false, false);       \
      auto va = __builtin_amdgcn_permlane16_swap(uu[0], uu[0], false, false); \
      auto vb = __builtin_amdgcn_permlane16_swap(uu[1], uu[1], false, false); \
      tA0 = __builtin_bit_cast(int, __builtin_amdgcn_cvt_pkrtz(               \
                __builtin_bit_cast(float, va[0]),                             \
                __builtin_bit_cast(float, va[1])));                           \
      tB0 = __builtin_bit_cast(int, __builtin_amdgcn_cvt_pkrtz(               \
                __builtin_bit_cast(float, vb[0]),                             \
                __builtin_bit_cast(float, vb[1])));                           \
    } else {                                                                  \
      int a16 = __builtin_amdgcn_ds_bpermute(adr16, wi);                      \
      int a32 = __builtin_amdgcn_ds_bpermute(adr32, wi);                      \
      int a48 = __builtin_amdgcn_ds_bpermute(adr48, wi);                      \
      tA0 = __builtin_bit_cast(int, __builtin_amdgcn_cvt_pkrtz(               \
                w, __builtin_bit_cast(float, a16)));                          \
      tB0 = __builtin_bit_cast(int, __builtin_amdgcn_cvt_pkrtz(               \
                __builtin_bit_cast(float, a32),                               \
                __builtin_bit_cast(float, a48)));                             \
    }                                                                         \
    TREE15(tA)                                                                \
    TREE15(tB)                                                                \
    float s0 = 0.f, s1 = 0.f, s2 = 0.f, s3 = 0.f;                             \
    FD(s0, tA0, Rh0);   FD(s1, tA1, Rh1);   FD(s0, tA2, Rh2);   FD(s1, tA3, Rh3);   \
    FD(s0, tA4, Rh4);   FD(s1, tA5, Rh5);   FD(s0, tA6, Rh6);   FD(s1, tA7, Rh7);   \
    FD(s0, tA8, Rh8);   FD(s1, tA9, Rh9);   FD(s0, tA10, Rh10); FD(s1, tA11, Rh11); \
    FD(s0, tA12, Rh12); FD(s1, tA13, Rh13); FD(s0, tA14, Rh14); FD(s1, tA15, Rh15); \
    FD(s2, tB0, Rh16);  FD(s3, tB1, Rh17);  FD(s2, tB2, Rh18);  FD(s3, tB3, Rh19);  \
    FD(s2, tB4, Rh20);  FD(s3, tB5, Rh21);  FD(s2, tB6, Rh22);  FD(s3, tB7, Rh23);  \
    FD(s2, tB8, Rh24);  FD(s3, tB9, Rh25);  FD(s2, tB10, Rh26); FD(s3, tB11, Rh27); \
    FD(s2, tB12, Rh28); FD(s3, tB13, Rh29); FD(s2, tB14, Rh30); FD(s3, tB15, Rh31); \
    w = ((s0 + s1) + (s2 + s3)) * KE;                                         \
  } while (0)

// Whole fwd/bwd loops as macros so the usePerm branch is hoisted OUT of the
// 512-step loop (manual unswitching; P is a literal inside).
#define FWD_BODY(P)                                                           \
  {                                                                           \
    float a0 = start[lane] + sc[lane];                                        \
    float m0 = rfl_f(a0);                                                     \
    float w = __expf(a0 - m0) * 16.f;                                         \
    int e2 = -4;                                                              \
    float b0 = sc[1 * NL + lane], b1 = sc[2 * NL + lane];                     \
    float b2 = sc[3 * NL + lane], b3 = sc[4 * NL + lane];                     \
    for (int i = 0; i < 128; i++) {                                           \
      int tb = 5 + 4 * i;                                                     \
      float n0 = sc[(tb + 0) * NL + lane], n1 = sc[(tb + 1) * NL + lane];     \
      float n2 = sc[(tb + 2) * NL + lane], n3 = sc[(tb + 3) * NL + lane];     \
      float E0 = __expf(b0), E1 = __expf(b1), E2 = __expf(b2), E3 = __expf(b3); \
      CRF_STEP(E0, P); CRF_STEP(E1, P); CRF_STEP(E2, P); CRF_STEP(E3, P);     \
      b0 = n0; b1 = n1; b2 = n2; b3 = n3;                                     \
    }                                                                         \
    wsA[b * NL + lane] = m0 + (float)e2 * LN2 + __logf(w);                    \
  }

#define BWD_BODY(P)                                                           \
  {                                                                           \
    float a0 = endv[lane] + sc[(NT - 1) * NL + lane];                         \
    float m0 = rfl_f(a0);                                                     \
    float w = __expf(a0 - m0) * 16.f;                                         \
    int e2 = -4;                                                              \
    float b0 = sc[1022 * NL + lane], b1 = sc[1021 * NL + lane];               \
    float b2 = sc[1020 * NL + lane], b3 = sc[1019 * NL + lane];               \
    for (int i = 0; i < 127; i++) {                                           \
      int tb = 1018 - 4 * i;                                                  \
      float n0 = sc[(tb - 0) * NL + lane], n1 = sc[(tb - 1) * NL + lane];     \
      float n2 = sc[(tb - 2) * NL + lane], n3 = sc[(tb - 3) * NL + lane];     \
      float E0 = __expf(b0), E1 = __expf(b1), E2 = __expf(b2), E3 = __expf(b3); \
      CRF_STEP(E0, P); CRF_STEP(E1, P); CRF_STEP(E2, P); CRF_STEP(E3, P);     \
      b0 = n0; b1 = n1; b2 = n2; b3 = n3;                                     \
    }                                                                         \
    CRF_STEP(__expf(sc[514 * NL + lane]), P);                                 \
    CRF_STEP(__expf(sc[513 * NL + lane]), P);                                 \
    CRF_STEP(1.0f, P);                                                        \
    wsB[b * NL + lane] = m0 + (float)e2 * LN2 + __logf(w);                    \
  }

#define MKRH(N, SRC)                                                          \
  const h2v Rh##N = __builtin_amdgcn_cvt_pkrtz(                               \
      __expf(Tb[((SRC) & 255) * str]), __expf(Tb[(((SRC) >> 8) & 255) * str]));

#define COVER(x) cov |= (1ull << ((x) & 63)) | (1ull << (((x) >> 8) & 63));
#define SELA(N) int jA##N = usePerm ? pA##N : fA##N;
#define SELB(N) int jB##N = usePerm ? pB##N : fB##N;

// Blocks 0..255: forward chains. 256..511: backward chains. 512..767: gold path.
// amdgpu_waves_per_eu(1,1): round-3 falsified the launch_bounds fix — VGPR
// stayed at 40 (= allocator still targeting the 64-VGPR / 8-wave boundary,
// spilling Rh through AGPRs: VALU cy/step doubled, +32 accvgpr reads). Max=1
// wave/EU grants the full 512-VGPR budget. Only ~3 waves/CU exist anyway.
__global__ __launch_bounds__(64)
__attribute__((amdgpu_waves_per_eu(1, 1)))
void fb_kernel(const float* __restrict__ scores,
               const int* __restrict__ targets,
               const float* __restrict__ start,
               const float* __restrict__ Tm,
               const float* __restrict__ endv,
               float* __restrict__ wsA,
               float* __restrict__ wsB,
               float* __restrict__ wsG) {
  const int lane = threadIdx.x;
  const int bb = blockIdx.x;

  if (bb >= 2 * NB) {  // ---- gold path: one wave per batch ----
    const int b = bb - 2 * NB;
    const int* tg = targets + b * NT;
    const float* sc = scores + (size_t)b * NT * NL;
    float acc = 0.f;
    for (int t = lane; t < NT; t += 64) {
      int c = tg[t];
      acc += sc[t * NL + c];
      if (t > 0) acc += Tm[c * NL + tg[t - 1]];  // T_mat[cur, prev]
    }
#pragma unroll
    for (int off = 32; off > 0; off >>= 1) acc += __shfl_xor(acc, off, 64);
    if (lane == 0) wsG[b] = acc + start[tg[0]] + endv[tg[NT - 1]];
    return;
  }

  const bool bwd = bb >= NB;
  const int b = bwd ? bb - NB : bb;
  const float* sc = scores + (size_t)b * NT * NL;
  const float LN2 = 0.69314718055994530942f;

  const int adr16 = (lane ^ 16) << 2;  // bpermute fallback addresses
  const int adr32 = (lane ^ 32) << 2;
  const int adr48 = (lane ^ 48) << 2;

  // ---- index probe: run the EXACT permlane+pack+DPP sequence on the lane id.
  // Every op is a deterministic bit-pattern-agnostic permutation, so the probe
  // reports the true slot->state map regardless of permlane swap direction or
  // builtin return order (round-1's unknowns). Rh is loaded in probe order.
  int idv = lane;
  auto uI = __builtin_amdgcn_permlane32_swap(idv, idv, false, false);
  auto vaI = __builtin_amdgcn_permlane16_swap(uI[0], uI[0], false, false);
  auto vbI = __builtin_amdgcn_permlane16_swap(uI[1], uI[1], false, false);
  int pA0 = (vaI[0] & 63) | ((vaI[1] & 63) << 8);
  int pB0 = (vbI[0] & 63) | ((vbI[1] & 63) << 8);
  TREE15(pA)
  TREE15(pB)

  // Coverage guard: the probe compensates ORDER but not duplicates/holes.
  unsigned long long cov = 0;
  COVER(pA0) COVER(pA1) COVER(pA2) COVER(pA3) COVER(pA4) COVER(pA5)
  COVER(pA6) COVER(pA7) COVER(pA8) COVER(pA9) COVER(pA10) COVER(pA11)
  COVER(pA12) COVER(pA13) COVER(pA14) COVER(pA15)
  COVER(pB0) COVER(pB1) COVER(pB2) COVER(pB3) COVER(pB4) COVER(pB5)
  COVER(pB6) COVER(pB7) COVER(pB8) COVER(pB9) COVER(pB10) COVER(pB11)
  COVER(pB12) COVER(pB13) COVER(pB14) COVER(pB15)
  const bool usePerm = __all(cov == ~0ull);

  // Fallback probe: bpermute roots (round-3-verified path): tA0=(w, w[l^16]),
  // tB0=(w[l^32], w[l^48]).
  int fA0 = lane | ((lane ^ 16) << 8);
  int fB0 = (lane ^ 32) | ((lane ^ 48) << 8);
  TREE15(fA)
  TREE15(fB)

  SELA(0) SELA(1) SELA(2) SELA(3) SELA(4) SELA(5) SELA(6) SELA(7)
  SELA(8) SELA(9) SELA(10) SELA(11) SELA(12) SELA(13) SELA(14) SELA(15)
  SELB(0) SELB(1) SELB(2) SELB(3) SELB(4) SELB(5) SELB(6) SELB(7)
  SELB(8) SELB(9) SELB(10) SELB(11) SELB(12) SELB(13) SELB(14) SELB(15)

  // f16 transition table in probe order:
  //  fwd r(p) = exp(T[lane][p])   (Tb = Tm + lane*NL, str = 1)
  //  bwd r(p) = exp(T[p][lane])   (Tb = Tm + lane,    str = NL)
  const float* Tb = bwd ? (Tm + lane) : (Tm + lane * NL);
  const int str = bwd ? NL : 1;
  MKRH(0, jA0)   MKRH(1, jA1)   MKRH(2, jA2)   MKRH(3, jA3)
  MKRH(4, jA4)   MKRH(5, jA5)   MKRH(6, jA6)   MKRH(7, jA7)
  MKRH(8, jA8)   MKRH(9, jA9)   MKRH(10, jA10) MKRH(11, jA11)
  MKRH(12, jA12) MKRH(13, jA13) MKRH(14, jA14) MKRH(15, jA15)
  MKRH(16, jB0)  MKRH(17, jB1)  MKRH(18, jB2)  MKRH(19, jB3)
  MKRH(20, jB4)  MKRH(21, jB5)  MKRH(22, jB6)  MKRH(23, jB7)
  MKRH(24, jB8)  MKRH(25, jB9)  MKRH(26, jB10) MKRH(27, jB11)
  MKRH(28, jB12) MKRH(29, jB13) MKRH(30, jB14) MKRH(31, jB15)

  if (!bwd) {
    if (usePerm) FWD_BODY(1) else FWD_BODY(0)
  } else {
    if (usePerm) BWD_BODY(1) else BWD_BODY(0)
  }
}

// Parallel combine: 16 waves; wave wv lse-reduces batches {wv, wv+16, ...}.
__global__ __launch_bounds__(1024) void combine_kernel(const float* __restrict__ wsA,
                                                       const float* __restrict__ wsB,
                                                       const float* __restrict__ wsG,
                                                       float* __restrict__ out) {
  const int tid = threadIdx.x;
  const int lane = tid & 63;
  const int wv = tid >> 6;  // 0..15
  __shared__ float losses[NB];
  __shared__ float red[4];

  for (int b = wv; b < NB; b += 16) {
    float v = wsA[b * NL + lane] + wsB[b * NL + lane];
    float m = v;
#pragma unroll
    for (int off = 32; off > 0; off >>= 1) m = fmaxf(m, __shfl_xor(m, off, 64));
    float s = __expf(v - m);
#pragma unroll
    for (int off = 32; off > 0; off >>= 1) s += __shfl_xor(s, off, 64);
    if (lane == 0) losses[b] = (m + __logf(s)) - wsG[b];
  }
  __syncthreads();

  if (tid < NB) {
    float loss = losses[tid];
#pragma unroll
    for (int off = 32; off > 0; off >>= 1) loss += __shfl_xor(loss, off, 64);
    if ((tid & 63) == 0) red[tid >> 6] = loss;
  }
  __syncthreads();
  if (tid == 0) out[0] = (red[0] + red[1] + red[2] + red[3]) * (1.0f / NB);
}

extern "C" void kernel_launch(void* const* d_in, const int* in_sizes, int n_in,
                              void* d_out, int out_size, void* d_ws, size_t ws_size,
                              hipStream_t stream) {
  const float* scores = (const float*)d_in[0];
  const int* targets = (const int*)d_in[1];
  const float* start = (const float*)d_in[2];
  const float* Tm = (const float*)d_in[3];
  const float* endv = (const float*)d_in[4];
  float* out = (float*)d_out;

  float* wsA = (float*)d_ws;       // [NB*NL] alpha_512, [batch][state]
  float* wsB = wsA + NB * NL;      // [NB*NL] beta_512, [batch][state]
  float* wsG = wsB + NB * NL;      // [NB] gold path scores

  fb_kernel<<<3 * NB, 64, 0, stream>>>(scores, targets, start, Tm, endv, wsA, wsB, wsG);
  combine_kernel<<<1, 1024, 0, stream>>>(wsA, wsB, wsG, out);
}

// Round 5
// 202.545 us; speedup vs baseline: 1.1679x; 1.1679x over previous
//
#include <hip/hip_runtime.h>

#define NB 256
#define NT 1024
#define NL 64

typedef __fp16 h2v __attribute__((ext_vector_type(2)));

__device__ __forceinline__ float rfl_f(float v) {
  return __builtin_bit_cast(float, __builtin_amdgcn_readfirstlane(__builtin_bit_cast(int, v)));
}

// partner = value from lane^1, via DPP quad_perm [1,0,3,2] (VALU, no LDS pipe)
__device__ __forceinline__ float dpp_xor1(float v) {
  int i = __builtin_bit_cast(int, v);
  int r = __builtin_amdgcn_update_dpp(i, i, 0xB1, 0xF, 0xF, false);
  return __builtin_bit_cast(float, r);
}

#define DOT4(P, B)                                                            \
  s0 = __builtin_amdgcn_fdot2(__builtin_bit_cast(h2v, (P).x), Rh[(B) + 0], s0, false); \
  s1 = __builtin_amdgcn_fdot2(__builtin_bit_cast(h2v, (P).y), Rh[(B) + 1], s1, false); \
  s2 = __builtin_amdgcn_fdot2(__builtin_bit_cast(h2v, (P).z), Rh[(B) + 2], s2, false); \
  s3 = __builtin_amdgcn_fdot2(__builtin_bit_cast(h2v, (P).w), Rh[(B) + 3], s3, false);

// One CRF step — BIT-IDENTICAL to the round-0 verified kernel (93us, absmax 0).
// Rounds 1-4 proved the DPP-tree/permlane/bpermute restructures all cost ~690
// cy/step regardless of register allocation; this LDS-broadcast step is the
// only structure measured at 436 cy/step. Do not touch.
#define CRF_STEP(EF)                                                          \
  do {                                                                        \
    float wn = dpp_xor1(w);                                                   \
    h2v pk = __builtin_amdgcn_cvt_pkrtz(w, wn);                               \
    lb[wslot] = __builtin_bit_cast(int, pk);                                  \
    int4 P0 = lbv[0], P1 = lbv[1], P2 = lbv[2], P3 = lbv[3];                  \
    int4 P4 = lbv[4], P5 = lbv[5], P6 = lbv[6], P7 = lbv[7];                  \
    int e5 = (P0.x >> 10) & 0x1f;                                             \
    float K = __builtin_bit_cast(float, (130 - e5) << 23);                    \
    float KE = K * (EF);                                                      \
    e2 += e5 - 3;                                                             \
    float s0 = 0.f, s1 = 0.f, s2 = 0.f, s3 = 0.f;                             \
    DOT4(P0, 0); DOT4(P1, 4); DOT4(P2, 8); DOT4(P3, 12);                      \
    DOT4(P4, 16); DOT4(P5, 20); DOT4(P6, 24); DOT4(P7, 28);                   \
    w = ((s0 + s1) + (s2 + s3)) * KE;                                         \
  } while (0)

#define AQ __ATOMIC_ACQUIRE
#define RL __ATOMIC_RELEASE
#define SCOPE __HIP_MEMORY_SCOPE_AGENT

// Single fused kernel. Blocks 0..255: fwd chains (publish alpha via flagF).
// 256..511: bwd chains (keep beta in regs, spin on flagF/flagG, compute the
// per-batch loss in-wave, last one reduces). 512..767: gold path (publish via
// flagG). Removes the second kernel launch: rounds 0-3 showed a constant
// ~83-91us residue (total - fb) that did NOT shrink when combine was
// parallelized -> it's dispatch/sync overhead, not combine execution.
// Co-residency: 768 one-wave blocks = 3 waves/CU << capacity, spins are safe.
__global__ __launch_bounds__(64) void fb_kernel(const float* __restrict__ scores,
                                                const int* __restrict__ targets,
                                                const float* __restrict__ start,
                                                const float* __restrict__ Tm,
                                                const float* __restrict__ endv,
                                                float* __restrict__ wsA,
                                                float* __restrict__ wsG,
                                                float* __restrict__ wsL,
                                                int* __restrict__ flagF,
                                                int* __restrict__ flagG,
                                                int* __restrict__ cnt,
                                                float* __restrict__ out) {
  const int lane = threadIdx.x;
  const int bb = blockIdx.x;

  if (bb >= 2 * NB) {  // ---- gold path: one wave per batch ----
    const int b = bb - 2 * NB;
    const int* tg = targets + b * NT;
    const float* sc = scores + (size_t)b * NT * NL;
    float acc = 0.f;
    for (int t = lane; t < NT; t += 64) {
      int c = tg[t];
      acc += sc[t * NL + c];
      if (t > 0) acc += Tm[c * NL + tg[t - 1]];  // T_mat[cur, prev]
    }
#pragma unroll
    for (int off = 32; off > 0; off >>= 1) acc += __shfl_xor(acc, off, 64);
    if (lane == 0) wsG[b] = acc + start[tg[0]] + endv[tg[NT - 1]];
    __threadfence();
    if (lane == 0) __hip_atomic_store(&flagG[b], 1, RL, SCOPE);
    return;
  }

  __shared__ int4 lbv_s[16];        // 64 words: 0..31 = consumed pairs, 32..63 = scratch
  int* lb = (int*)lbv_s;
  const int4* lbv = lbv_s;
  const int wslot = (lane & 1) * 32 + (lane >> 1);  // 2 lanes/bank -> conflict-free

  const bool bwd = bb >= NB;
  const int b = bwd ? bb - NB : bb;
  const float* sc = scores + (size_t)b * NT * NL;
  const float LN2 = 0.69314718055994530942f;

  // f16x2 transition table: fwd Rh[k] = (exp(T[lane][2k]), exp(T[lane][2k+1]))
  //                         bwd Rh[k] = (exp(T[2k][lane]), exp(T[2k+1][lane]))
  const float* Tb = bwd ? (Tm + lane) : (Tm + lane * NL);
  const int str = bwd ? NL : 1;
  h2v Rh[32];
#pragma unroll
  for (int k = 0; k < 32; k++)
    Rh[k] = __builtin_amdgcn_cvt_pkrtz(__expf(Tb[(2 * k) * str]),
                                       __expf(Tb[(2 * k + 1) * str]));

  if (!bwd) {
    float a0 = start[lane] + sc[lane];  // alpha_0
    float m0 = rfl_f(a0);
    float w = __expf(a0 - m0) * 16.f;   // keep w_0 in f16-normal range
    int e2 = -4;

    float buf[4];
#pragma unroll
    for (int k = 0; k < 4; k++) buf[k] = sc[(1 + k) * NL + lane];

    for (int i = 0; i < 128; i++) {  // 512 steps: t = 1..512
      float nb4[4];
      int tb = 5 + 4 * i;  // prefetch (max t=516 < 1024)
#pragma unroll
      for (int k = 0; k < 4; k++) nb4[k] = sc[(tb + k) * NL + lane];
      float Ev[4];
#pragma unroll
      for (int k = 0; k < 4; k++) Ev[k] = __expf(buf[k]);  // off critical chain
      CRF_STEP(Ev[0]);
      CRF_STEP(Ev[1]);
      CRF_STEP(Ev[2]);
      CRF_STEP(Ev[3]);
#pragma unroll
      for (int k = 0; k < 4; k++) buf[k] = nb4[k];
    }
    wsA[b * NL + lane] = m0 + (float)e2 * LN2 + __logf(w);  // alpha_512, coalesced
    __threadfence();  // wave-wide vmcnt drain + L2 writeback before publish
    if (lane == 0) __hip_atomic_store(&flagF[b], 1, RL, SCOPE);
  } else {
    float a0 = endv[lane] + sc[(NT - 1) * NL + lane];
    float m0 = rfl_f(a0);
    float w = __expf(a0 - m0) * 16.f;
    int e2 = -4;

    float buf[4];
#pragma unroll
    for (int k = 0; k < 4; k++) buf[k] = sc[(1022 - k) * NL + lane];

    for (int i = 0; i < 127; i++) {  // 508 steps: te = 1022..515
      float nb4[4];
      int tb = 1018 - 4 * i;  // prefetch (min 511 >= 0)
#pragma unroll
      for (int k = 0; k < 4; k++) nb4[k] = sc[(tb - k) * NL + lane];
      float Ev[4];
#pragma unroll
      for (int k = 0; k < 4; k++) Ev[k] = __expf(buf[k]);
      CRF_STEP(Ev[0]);
      CRF_STEP(Ev[1]);
      CRF_STEP(Ev[2]);
      CRF_STEP(Ev[3]);
#pragma unroll
      for (int k = 0; k < 4; k++) buf[k] = nb4[k];
    }
    CRF_STEP(__expf(sc[514 * NL + lane]));
    CRF_STEP(__expf(sc[513 * NL + lane]));
    CRF_STEP(1.0f);  // final matvec-only step -> beta_512
    float bv = m0 + (float)e2 * LN2 + __logf(w);  // beta_512, stays in reg

    // ---- fused combine: wait for fwd twin, lse(alpha+beta), subtract gold ----
    while (__hip_atomic_load(&flagF[b], AQ, SCOPE) == 0) __builtin_amdgcn_s_sleep(2);
    float v = wsA[b * NL + lane] + bv;
    float m = v;
#pragma unroll
    for (int off = 32; off > 0; off >>= 1) m = fmaxf(m, __shfl_xor(m, off, 64));
    float s = __expf(v - m);
#pragma unroll
    for (int off = 32; off > 0; off >>= 1) s += __shfl_xor(s, off, 64);
    while (__hip_atomic_load(&flagG[b], AQ, SCOPE) == 0) __builtin_amdgcn_s_sleep(2);
    float loss = (m + __logf(s)) - wsG[b];

    int old = -1;
    if (lane == 0) {
      wsL[b] = loss;
      __threadfence();
      old = __hip_atomic_fetch_add(cnt, 1, __ATOMIC_ACQ_REL, SCOPE);
    }
    old = __shfl(old, 0, 64);
    if (old == NB - 1) {  // ---- finisher: deterministic fixed-order reduction ----
      __threadfence();
      float t0 = __builtin_bit_cast(float, __hip_atomic_load((int*)&wsL[lane], AQ, SCOPE));
      float t1 = __builtin_bit_cast(float, __hip_atomic_load((int*)&wsL[lane + 64], AQ, SCOPE));
      float t2 = __builtin_bit_cast(float, __hip_atomic_load((int*)&wsL[lane + 128], AQ, SCOPE));
      float t3 = __builtin_bit_cast(float, __hip_atomic_load((int*)&wsL[lane + 192], AQ, SCOPE));
      float tot = (t0 + t1) + (t2 + t3);
#pragma unroll
      for (int off = 32; off > 0; off >>= 1) tot += __shfl_xor(tot, off, 64);
      if (lane == 0) out[0] = tot * (1.0f / NB);
    }
  }
}

extern "C" void kernel_launch(void* const* d_in, const int* in_sizes, int n_in,
                              void* d_out, int out_size, void* d_ws, size_t ws_size,
                              hipStream_t stream) {
  const float* scores = (const float*)d_in[0];
  const int* targets = (const int*)d_in[1];
  const float* start = (const float*)d_in[2];
  const float* Tm = (const float*)d_in[3];
  const float* endv = (const float*)d_in[4];
  float* out = (float*)d_out;

  // Workspace layout. flags+counter are re-zeroed every replay by the memset
  // (graph-capturable; the harness's own reset() uses hipMemsetAsync too).
  int* flagF = (int*)d_ws;             // [NB]
  int* flagG = flagF + NB;             // [NB]
  int* cnt = flagG + NB;               // [1] (+63 pad)
  float* wsG = (float*)(cnt + 64);     // [NB] gold path scores
  float* wsL = wsG + NB;               // [NB] per-batch losses
  float* wsA = wsL + NB;               // [NB*NL] alpha_512, [batch][state]

  hipMemsetAsync(flagF, 0, (2 * NB + 64) * sizeof(int), stream);
  fb_kernel<<<3 * NB, 64, 0, stream>>>(scores, targets, start, Tm, endv,
                                       wsA, wsG, wsL, flagF, flagG, cnt, out);
}